// Round 5
// baseline (148.306 us; speedup 1.0000x reference)
//
#include <hip/hip_runtime.h>

// DetectionLoss: NB=3, C=20, S=7, D=35, B=8192 -> 401408 cells, ~112 MB read.
// R5: NO LDS, NO DMA, NO barriers. One cell per thread, direct global->reg
// loads. Each cell is 140 B contiguous; a wave's 64 cells span a contiguous
// 8.96 KB window, so every cache line is fetched exactly once (HBM-perfect).
// Cost is only L1 lookup serialization, hidden by ~24 waves/CU of TLP.
// R3/R4's LDS-DMA structures both plateaued at ~35us (~3.2 TB/s effective);
// fillBuffer on the same device does 6.5 TB/s -> the LDS round-trip (DMA
// issue + vmcnt drain + 70 scalar ds_reads + barriers) was the limiter.

#define NBOX 3
#define NCLS 20
#define SDIM 7
#define DCH  35
#define NTHREADS 256

// 16-byte vector load with only 4-byte alignment guarantee (cell base = 140B*i)
typedef float float4u __attribute__((ext_vector_type(4), aligned(4)));

__global__ __launch_bounds__(NTHREADS) void detloss_kernel(
    const float* __restrict__ out_g, const float* __restrict__ tgt_g,
    float* __restrict__ partials, float inv_nB)
{
    __shared__ float s_part[NTHREADS / 64];

    const int tid  = threadIdx.x;
    const long long cell = (long long)blockIdx.x * NTHREADS + tid;
    const float* ob = out_g + cell * DCH;
    const float* gb = tgt_g + cell * DCH;

    // ---- direct vector loads: 9 + 9 overlapping dwordx4, all issued up front ----
    float o[36], g[36];
    #pragma unroll
    for (int k = 0; k < 8; ++k) {
        *(float4u*)&o[4 * k] = *(const float4u*)(ob + 4 * k);   // floats 0..31
        *(float4u*)&g[4 * k] = *(const float4u*)(gb + 4 * k);
    }
    { // floats 31..34 (31 loaded twice — harmless, keeps 4B-aligned dwordx4)
        float4u to = *(const float4u*)(ob + 31);
        float4u tg = *(const float4u*)(gb + 31);
        o[31] = to.x; o[32] = to.y; o[33] = to.z; o[34] = to.w;
        g[31] = tg.x; g[32] = tg.y; g[33] = tg.z; g[34] = tg.w;
    }

    // ---- per-cell loss, exactly as reference ----
    const float tx  = g[0] / 7.0f, ty = g[1] / 7.0f;
    const float thw = 0.5f * g[2], thh = 0.5f * g[3];
    const float tx1 = tx - thw, ty1 = ty - thh;
    const float tx2 = tx + thw, ty2 = ty + thh;
    const float a2  = (tx2 - tx1) * (ty2 - ty1);

    const float conf_t = g[4];
    const float obj    = (conf_t == 1.0f) ? 1.0f : 0.0f;
    const float noobj  = (conf_t == 0.0f) ? 1.0f : 0.0f;

    float biou = -__builtin_inff();   // strict > => first-index-wins (matches argmax)
    float conf_sq = 0.0f;
    // best-box values tracked via selects (no runtime indexing of reg arrays)
    float bo0 = 0.f, bo1 = 0.f, bo2 = 0.f, bo3 = 0.f, bo4 = 0.f;
    float bg0 = 0.f, bg1 = 0.f, bg2 = 0.f, bg3 = 0.f;

    #pragma unroll
    for (int i = 0; i < NBOX; ++i) {
        const float px  = o[5*i]   / 7.0f;
        const float py  = o[5*i+1] / 7.0f;
        const float phw = 0.5f * o[5*i+2];
        const float phh = 0.5f * o[5*i+3];
        const float px1 = px - phw, py1 = py - phh;
        const float px2 = px + phw, py2 = py + phh;

        const float ltx = fmaxf(px1, tx1), lty = fmaxf(py1, ty1);
        const float rbx = fminf(px2, tx2), rby = fminf(py2, ty2);
        const float w = fmaxf(rbx - ltx, 0.0f);
        const float h = fmaxf(rby - lty, 0.0f);
        const float inter = w * h;
        const float a1 = (px2 - px1) * (py2 - py1);
        const float iou = inter / (a1 + a2 - inter);

        const bool better = iou > biou;
        biou = better ? iou      : biou;
        bo0  = better ? o[5*i]   : bo0;
        bo1  = better ? o[5*i+1] : bo1;
        bo2  = better ? o[5*i+2] : bo2;
        bo3  = better ? o[5*i+3] : bo3;
        bo4  = better ? o[5*i+4] : bo4;
        bg0  = better ? g[5*i]   : bg0;
        bg1  = better ? g[5*i+1] : bg1;
        bg2  = better ? g[5*i+2] : bg2;
        bg3  = better ? g[5*i+3] : bg3;

        const float dc = o[5*i+4] - g[5*i+4];
        conf_sq += dc * dc;
    }

    float loss = 0.5f * noobj * conf_sq;

    const float dx = bo0 - bg0;
    const float dy = bo1 - bg1;
    const float xyl = dx*dx + dy*dy;
    const float dw = sqrtf(bo2) - sqrtf(bg2);
    const float dh = sqrtf(bo3) - sqrtf(bg3);
    const float whl = dw*dw + dh*dh;
    const float dcf = bo4 - biou;
    const float contain = dcf * dcf;

    float cls = 0.0f;
    #pragma unroll
    for (int c = 0; c < NCLS; ++c) {
        const float d = o[5*NBOX + c] - g[5*NBOX + c];
        cls += d * d;
    }

    loss += obj * (5.0f * (xyl + whl) + contain + cls);
    loss *= inv_nB;

    // ---- wave shfl -> LDS -> one partial per block ----
    #pragma unroll
    for (int off = 32; off > 0; off >>= 1)
        loss += __shfl_down(loss, off);
    if ((tid & 63) == 0) s_part[tid >> 6] = loss;
    __syncthreads();
    if (tid == 0) {
        float tot = s_part[0];
        #pragma unroll
        for (int w = 1; w < NTHREADS / 64; ++w) tot += s_part[w];
        partials[blockIdx.x] = tot;
    }
}

__global__ __launch_bounds__(1024) void reduce_kernel(
    const float* __restrict__ partials, float* __restrict__ out, int n)
{
    __shared__ float s[1024 / 64];
    float v = 0.0f;
    for (int i = threadIdx.x; i < n; i += 1024) v += partials[i];
    #pragma unroll
    for (int off = 32; off > 0; off >>= 1)
        v += __shfl_down(v, off);
    if ((threadIdx.x & 63) == 0) s[threadIdx.x >> 6] = v;
    __syncthreads();
    if (threadIdx.x == 0) {
        float t = 0.0f;
        #pragma unroll
        for (int w = 0; w < 1024 / 64; ++w) t += s[w];
        out[0] = t;
    }
}

extern "C" void kernel_launch(void* const* d_in, const int* in_sizes, int n_in,
                              void* d_out, int out_size, void* d_ws, size_t ws_size,
                              hipStream_t stream) {
    const float* out_p = (const float*)d_in[0];
    const float* tgt_p = (const float*)d_in[1];
    float* res  = (float*)d_out;
    float* part = (float*)d_ws;

    const int n_cells = in_sizes[0] / DCH;            // 401408
    const int nB = n_cells / (SDIM * SDIM);           // 8192
    const float inv_nB = 1.0f / (float)nB;

    const int blocks = n_cells / NTHREADS;            // 1568 (exact)
    hipLaunchKernelGGL(detloss_kernel, dim3(blocks), dim3(NTHREADS), 0, stream,
                       out_p, tgt_p, part, inv_nB);
    hipLaunchKernelGGL(reduce_kernel, dim3(1), dim3(1024), 0, stream,
                       part, res, blocks);
}